// Round 1
// baseline (482.915 us; speedup 1.0000x reference)
//
#include <hip/hip_runtime.h>

#define NEXP 5
#define MAXF 128
#define NOUT 512

// ws int layout: [0..4]=cnt, [8..12]=cur, [16..20]=segstart, [24..29]=gbase[6], [64..]=perm

__global__ void misl_zero(int* ws) {
    if (threadIdx.x < 32) ws[threadIdx.x] = 0;
}

__global__ void misl_hist(const int* __restrict__ feat, int* ws, int n) {
    int t = blockIdx.x * 256 + threadIdx.x;
    if (t < n) {
        int e = __ffs(feat[t]) - 4;   // 8->0, 16->1, 32->2, 64->3, 128->4
        atomicAdd(&ws[e], 1);
    }
}

__global__ void misl_offs(int* ws) {
    if (threadIdx.x == 0) {
        int s = 0, g = 0;
        for (int e = 0; e < NEXP; ++e) {
            ws[16 + e] = s;          // segment start (token index into perm)
            ws[8 + e]  = s;          // scatter cursor starts at segment start
            ws[24 + e] = g;          // padded group base (64-token groups)
            s += ws[e];
            g += (ws[e] + 63) >> 6;
        }
        ws[24 + NEXP] = g;           // total groups
    }
}

__global__ void misl_scatter(const int* __restrict__ feat, int* ws, int n) {
    int t = blockIdx.x * 256 + threadIdx.x;
    if (t < n) {
        int e = __ffs(feat[t]) - 4;
        int pos = atomicAdd(&ws[8 + e], 1);
        ws[64 + pos] = t;
    }
}

// lane = token (64 sorted same-expert tokens per wave); wave = 32-output tile.
// W addresses are wave-uniform -> scalar loads; inner loop ~pure v_fma with
// one SGPR operand. x per-lane in VGPRs, 8-wide k chunks.
__global__ __launch_bounds__(256) void misl_main(
    const float* __restrict__ x, const float* __restrict__ w,
    const float* __restrict__ b, const int* __restrict__ ws,
    float* __restrict__ out) {
    const int g  = blockIdx.x >> 2;       // token group
    const int ob = blockIdx.x & 3;        // 128-output block
    if (g >= ws[24 + NEXP]) return;

    int e = 0;
    #pragma unroll
    for (int i = 0; i < NEXP - 1; ++i)
        if (g >= ws[24 + i + 1]) e = i + 1;

    const int K    = 8 << e;
    const int lg   = g - ws[24 + e];
    const int cnte = ws[e];
    const int lane = threadIdx.x & 63;
    const int wv   = __builtin_amdgcn_readfirstlane(threadIdx.x >> 6);
    const int obase = ob * 128 + wv * 32;

    int li = lg * 64 + lane;
    const bool valid = (li < cnte);
    if (li >= cnte) li = cnte - 1;        // group exists => cnte >= 1
    const int tok = ws[64 + ws[16 + e] + li];

    const float* xr = x + (size_t)tok * MAXF;
    const float* wr = w + ((size_t)e * NOUT + obase) * MAXF;
    const float* br = b + e * NOUT + obase;

    float acc[32];
    #pragma unroll
    for (int o = 0; o < 32; ++o) acc[o] = br[o];

    for (int k0 = 0; k0 < K; k0 += 8) {
        const float4 xa = *(const float4*)(xr + k0);
        const float4 xb = *(const float4*)(xr + k0 + 4);
        const float xk0 = xa.x, xk1 = xa.y, xk2 = xa.z, xk3 = xa.w;
        const float xk4 = xb.x, xk5 = xb.y, xk6 = xb.z, xk7 = xb.w;
        #pragma unroll
        for (int o = 0; o < 32; ++o) {
            const float* wo = wr + o * MAXF + k0;
            float s = acc[o];
            s += xk0 * wo[0]; s += xk1 * wo[1];
            s += xk2 * wo[2]; s += xk3 * wo[3];
            s += xk4 * wo[4]; s += xk5 * wo[5];
            s += xk6 * wo[6]; s += xk7 * wo[7];
            acc[o] = s;
        }
    }

    if (valid) {
        float* orow = out + (size_t)tok * NOUT + obase;
        #pragma unroll
        for (int o = 0; o < 32; o += 4) {
            float4 v = make_float4(acc[o], acc[o + 1], acc[o + 2], acc[o + 3]);
            *(float4*)(orow + o) = v;
        }
    }
}

extern "C" void kernel_launch(void* const* d_in, const int* in_sizes, int n_in,
                              void* d_out, int out_size, void* d_ws, size_t ws_size,
                              hipStream_t stream) {
    const float* x    = (const float*)d_in[0];
    const int*   feat = (const int*)d_in[1];
    const float* w    = (const float*)d_in[2];
    const float* b    = (const float*)d_in[3];
    float* out = (float*)d_out;
    int*   ws  = (int*)d_ws;

    const int n  = in_sizes[1];           // B*S tokens = 32768
    const int nb = (n + 255) / 256;

    misl_zero<<<1, 64, 0, stream>>>(ws);
    misl_hist<<<nb, 256, 0, stream>>>(feat, ws, n);
    misl_offs<<<1, 64, 0, stream>>>(ws);
    misl_scatter<<<nb, 256, 0, stream>>>(feat, ws, n);

    const int gmax = (n + 63) / 64 + NEXP;    // padded-group upper bound
    misl_main<<<gmax * 4, 256, 0, stream>>>(x, w, b, ws, out);
}

// Round 2
// 173.775 us; speedup vs baseline: 2.7790x; 2.7790x over previous
//
#include <hip/hip_runtime.h>

#define NEXP 5
#define MAXF 128
#define NOUT 512

// ws int layout: [0..4]=cnt, [8..12]=cur, [16..20]=segstart, [24..29]=gbase[6], [64..]=perm

__global__ void misl_zero(int* ws) {
    if (threadIdx.x < 32) ws[threadIdx.x] = 0;
}

// Per-block LDS histogram -> 5 global atomics per block (not per thread).
__global__ void misl_hist(const int* __restrict__ feat, int* ws, int n) {
    __shared__ int lcnt[NEXP];
    const int tid = threadIdx.x;
    if (tid < NEXP) lcnt[tid] = 0;
    __syncthreads();
    const int t = blockIdx.x * 256 + tid;
    if (t < n) {
        const int e = __ffs(feat[t]) - 4;   // 8->0, 16->1, 32->2, 64->3, 128->4
        atomicAdd(&lcnt[e], 1);
    }
    __syncthreads();
    if (tid < NEXP) atomicAdd(&ws[tid], lcnt[tid]);
}

__global__ void misl_offs(int* ws) {
    if (threadIdx.x == 0) {
        int s = 0, g = 0;
        for (int e = 0; e < NEXP; ++e) {
            ws[16 + e] = s;          // segment start (token index into perm)
            ws[8 + e]  = s;          // scatter cursor starts at segment start
            ws[24 + e] = g;          // padded group base (64-token groups)
            s += ws[e];
            g += (ws[e] + 63) >> 6;
        }
        ws[24 + NEXP] = g;           // total groups
    }
}

// Rank-within-block via LDS atomics; block base via one global atomic per
// expert per block. Ordering within a segment is arbitrary but valid.
__global__ void misl_scatter(const int* __restrict__ feat, int* ws, int n) {
    __shared__ int lcnt[NEXP];
    __shared__ int lbase[NEXP];
    const int tid = threadIdx.x;
    if (tid < NEXP) lcnt[tid] = 0;
    __syncthreads();
    const int t = blockIdx.x * 256 + tid;
    int e = 0, r = 0;
    if (t < n) {
        e = __ffs(feat[t]) - 4;
        r = atomicAdd(&lcnt[e], 1);
    }
    __syncthreads();
    if (tid < NEXP) lbase[tid] = atomicAdd(&ws[8 + tid], lcnt[tid]);
    __syncthreads();
    if (t < n) ws[64 + lbase[e] + r] = t;
}

// lane = token (64 sorted same-expert tokens per wave); wave = 32-output tile.
// W addresses are wave-uniform; x per-lane in VGPRs, 8-wide k chunks.
__global__ __launch_bounds__(256) void misl_main(
    const float* __restrict__ x, const float* __restrict__ w,
    const float* __restrict__ b, const int* __restrict__ ws,
    float* __restrict__ out) {
    const int g  = blockIdx.x >> 2;       // token group
    const int ob = blockIdx.x & 3;        // 128-output block
    if (g >= ws[24 + NEXP]) return;

    int e = 0;
    #pragma unroll
    for (int i = 0; i < NEXP - 1; ++i)
        if (g >= ws[24 + i + 1]) e = i + 1;

    const int K    = 8 << e;
    const int lg   = g - ws[24 + e];
    const int cnte = ws[e];
    const int lane = threadIdx.x & 63;
    const int wv   = __builtin_amdgcn_readfirstlane(threadIdx.x >> 6);
    const int obase = ob * 128 + wv * 32;

    int li = lg * 64 + lane;
    const bool valid = (li < cnte);
    if (li >= cnte) li = cnte - 1;        // group exists => cnte >= 1
    const int tok = ws[64 + ws[16 + e] + li];

    const float* xr = x + (size_t)tok * MAXF;
    const float* wr = w + ((size_t)e * NOUT + obase) * MAXF;
    const float* br = b + e * NOUT + obase;

    float acc[32];
    #pragma unroll
    for (int o = 0; o < 32; ++o) acc[o] = br[o];

    for (int k0 = 0; k0 < K; k0 += 8) {
        const float4 xa = *(const float4*)(xr + k0);
        const float4 xb = *(const float4*)(xr + k0 + 4);
        #pragma unroll
        for (int o = 0; o < 32; ++o) {
            const float* wo = wr + o * MAXF + k0;
            const float4 w0 = *(const float4*)(wo);
            const float4 w1 = *(const float4*)(wo + 4);
            float s = acc[o];
            s += xa.x * w0.x; s += xa.y * w0.y;
            s += xa.z * w0.z; s += xa.w * w0.w;
            s += xb.x * w1.x; s += xb.y * w1.y;
            s += xb.z * w1.z; s += xb.w * w1.w;
            acc[o] = s;
        }
    }

    if (valid) {
        float* orow = out + (size_t)tok * NOUT + obase;
        #pragma unroll
        for (int o = 0; o < 32; o += 4) {
            float4 v = make_float4(acc[o], acc[o + 1], acc[o + 2], acc[o + 3]);
            *(float4*)(orow + o) = v;
        }
    }
}

extern "C" void kernel_launch(void* const* d_in, const int* in_sizes, int n_in,
                              void* d_out, int out_size, void* d_ws, size_t ws_size,
                              hipStream_t stream) {
    const float* x    = (const float*)d_in[0];
    const int*   feat = (const int*)d_in[1];
    const float* w    = (const float*)d_in[2];
    const float* b    = (const float*)d_in[3];
    float* out = (float*)d_out;
    int*   ws  = (int*)d_ws;

    const int n  = in_sizes[1];           // B*S tokens = 32768
    const int nb = (n + 255) / 256;

    misl_zero<<<1, 64, 0, stream>>>(ws);
    misl_hist<<<nb, 256, 0, stream>>>(feat, ws, n);
    misl_offs<<<1, 64, 0, stream>>>(ws);
    misl_scatter<<<nb, 256, 0, stream>>>(feat, ws, n);

    const int gmax = (n + 63) / 64 + NEXP;    // padded-group upper bound
    misl_main<<<gmax * 4, 256, 0, stream>>>(x, w, b, ws, out);
}